// Round 4
// baseline (342.161 us; speedup 1.0000x reference)
//
#include <hip/hip_runtime.h>
#include <stdint.h>
#include <stddef.h>

using short8 = __attribute__((ext_vector_type(8))) short;
using short4v = __attribute__((ext_vector_type(4))) short;
using f32x4  = __attribute__((ext_vector_type(4))) float;
using f32x16 = __attribute__((ext_vector_type(16))) float;
using bf16x8 = __attribute__((ext_vector_type(8))) __bf16;

#define DEVI __device__ __forceinline__

// round-to-nearest-even fp32 -> bf16 (bit pattern as short)
DEVI short bf16r(float f) {
  union { float f; uint32_t u; } x; x.f = f;
  uint32_t r = x.u + 0x7FFFu + ((x.u >> 16) & 1u);
  return (short)(r >> 16);
}

DEVI f32x4 mfma16(short8 a, short8 b, f32x4 c) {
  return __builtin_amdgcn_mfma_f32_16x16x32_bf16(
      __builtin_bit_cast(bf16x8, a), __builtin_bit_cast(bf16x8, b), c, 0, 0, 0);
}

DEVI f32x16 mfma32(short8 a, short8 b, f32x16 c) {
  return __builtin_amdgcn_mfma_f32_32x32x16_bf16(
      __builtin_bit_cast(bf16x8, a), __builtin_bit_cast(bf16x8, b), c, 0, 0, 0);
}

DEVI void gload_lds16(const void* g, void* l) {
  __builtin_amdgcn_global_load_lds(
      (const void __attribute__((address_space(1)))*)g,
      (void __attribute__((address_space(3)))*)l,
      16, 0, 0);
}

// v_exp_f32 computes 2^x
DEVI float fexp2(float x) {
  float r;
  asm("v_exp_f32 %0, %1" : "=v"(r) : "v"(x));
  return r;
}

// packed fp32->bf16: dst[15:0]=bf16(a), dst[31:16]=bf16(b)
DEVI unsigned cvtpk(float a, float b) {
  unsigned r;
  asm("v_cvt_pk_bf16_f32 %0, %1, %2" : "=v"(r) : "v"(a), "v"(b));
  return r;
}

// ---------------- fp32 -> bf16 conversion (weights) ----------------
__global__ void k_cvt(const float* __restrict__ src, short* __restrict__ dst, int n4) {
  int i = blockIdx.x * blockDim.x + threadIdx.x;
  if (i < n4) {
    f32x4 v = reinterpret_cast<const f32x4*>(src)[i];
    short4v o;
    o[0] = bf16r(v[0]); o[1] = bf16r(v[1]); o[2] = bf16r(v[2]); o[3] = bf16r(v[3]);
    reinterpret_cast<short4v*>(dst)[i] = o;
  }
}

// ---------------- GEMM: C(M,N) = (A(M,K) @ W(N,K)^T + bias) * alpha ----------------
// DUAL: blockIdx.z selects {Ap,Bw,bias,Cp} vs {Ap2,Bw2,bias2,Cp2} (fuses K/V proj)
template<bool A_F32, bool OUT_F32, bool DUAL>
__global__ __launch_bounds__(256) void k_gemm(
    const void* __restrict__ Ap, const short* __restrict__ Bw,
    const float* __restrict__ bias, void* __restrict__ Cp,
    const void* __restrict__ Ap2, const short* __restrict__ Bw2,
    const float* __restrict__ bias2, void* __restrict__ Cp2,
    int M, int N, int K, float alpha)
{
  if constexpr (DUAL) {
    if (blockIdx.z) { Ap = Ap2; Bw = Bw2; bias = bias2; Cp = Cp2; }
  }
  __shared__ short As[2][128 * 64];
  __shared__ short Bs[2][128 * 64];
  const int t = threadIdx.x;
  const int lane = t & 63;
  const int wid = t >> 6;
  const int wr = wid >> 1, wc = wid & 1;
  const int bm = blockIdx.y * 128;
  const int bn = blockIdx.x * 128;

  f32x4 acc[4][4];
  #pragma unroll
  for (int i = 0; i < 4; ++i)
    #pragma unroll
    for (int j = 0; j < 4; ++j) acc[i][j] = f32x4{0.f, 0.f, 0.f, 0.f};

  const int nt = K >> 6;

  auto stageB = [&](int buf, int k0) {
    #pragma unroll
    for (int i = 0; i < 4; ++i) {
      int lin = t * 16 + i * 4096;
      int a = lin ^ (((lin >> 7) & 7) << 4);
      int row = a >> 7;
      int col = (a & 127) >> 1;
      const short* g = Bw + (size_t)(bn + row) * K + k0 + col;
      gload_lds16(g, (char*)(&Bs[buf][0]) + (wid << 10) + (i << 12));
    }
  };
  auto stageA_bf16 = [&](int buf, int k0) {
    const short* A = (const short*)Ap;
    #pragma unroll
    for (int i = 0; i < 4; ++i) {
      int lin = t * 16 + i * 4096;
      int a = lin ^ (((lin >> 7) & 7) << 4);
      int row = a >> 7;
      int col = (a & 127) >> 1;
      const short* g = A + (size_t)(bm + row) * K + k0 + col;
      gload_lds16(g, (char*)(&As[buf][0]) + (wid << 10) + (i << 12));
    }
  };
  auto loadA_f32 = [&](int k0, float (&r)[4][8]) {
    const float* A = (const float*)Ap;
    #pragma unroll
    for (int i = 0; i < 4; ++i) {
      int idx = (t + i * 256) * 8;
      int row = idx >> 6;
      int col = idx & 63;
      const float* g = A + (size_t)(bm + row) * K + k0 + col;
      f32x4 v0 = *reinterpret_cast<const f32x4*>(g);
      f32x4 v1 = *reinterpret_cast<const f32x4*>(g + 4);
      r[i][0] = v0[0]; r[i][1] = v0[1]; r[i][2] = v0[2]; r[i][3] = v0[3];
      r[i][4] = v1[0]; r[i][5] = v1[1]; r[i][6] = v1[2]; r[i][7] = v1[3];
    }
  };
  auto writeA_f32 = [&](int buf, float (&r)[4][8]) {
    #pragma unroll
    for (int i = 0; i < 4; ++i) {
      int idx = (t + i * 256) * 8;
      int row = idx >> 6;
      int col = idx & 63;
      short8 s;
      #pragma unroll
      for (int e = 0; e < 8; ++e) s[e] = bf16r(r[i][e]);
      int byte = ((row << 7) + (col << 1)) ^ ((row & 7) << 4);
      *reinterpret_cast<short8*>((char*)(&As[buf][0]) + byte) = s;
    }
  };

  if constexpr (A_F32) {
    float r0[4][8];
    loadA_f32(0, r0);
    writeA_f32(0, r0);
  } else {
    stageA_bf16(0, 0);
  }
  stageB(0, 0);
  __syncthreads();

  int cur = 0;
  for (int kt = 0; kt < nt; ++kt) {
    float ra[4][8];
    const bool pf = (kt + 1 < nt);
    if (pf) {
      if constexpr (A_F32) loadA_f32((kt + 1) << 6, ra);
      else stageA_bf16(cur ^ 1, (kt + 1) << 6);
      stageB(cur ^ 1, (kt + 1) << 6);
    }
    #pragma unroll
    for (int kk = 0; kk < 2; ++kk) {
      const int kb = (kk * 32 + ((lane >> 4) << 3)) << 1;
      short8 af[4], bfr[4];
      #pragma unroll
      for (int i = 0; i < 4; ++i) {
        int row = wr * 64 + i * 16 + (lane & 15);
        int byte = ((row << 7) + kb) ^ ((row & 7) << 4);
        af[i] = *reinterpret_cast<const short8*>((const char*)(&As[cur][0]) + byte);
      }
      #pragma unroll
      for (int j = 0; j < 4; ++j) {
        int row = wc * 64 + j * 16 + (lane & 15);
        int byte = ((row << 7) + kb) ^ ((row & 7) << 4);
        bfr[j] = *reinterpret_cast<const short8*>((const char*)(&Bs[cur][0]) + byte);
      }
      #pragma unroll
      for (int i = 0; i < 4; ++i)
        #pragma unroll
        for (int j = 0; j < 4; ++j)
          acc[i][j] = mfma16(af[i], bfr[j], acc[i][j]);
    }
    if constexpr (A_F32) {
      if (pf) writeA_f32(cur ^ 1, ra);
    }
    __syncthreads();
    cur ^= 1;
  }

  #pragma unroll
  for (int j = 0; j < 4; ++j) {
    int col = bn + wc * 64 + j * 16 + (lane & 15);
    float bv = bias[col];
    #pragma unroll
    for (int i = 0; i < 4; ++i) {
      int row0 = bm + wr * 64 + i * 16 + ((lane >> 4) << 2);
      #pragma unroll
      for (int r = 0; r < 4; ++r) {
        float v = (acc[i][j][r] + bv) * alpha;
        if constexpr (OUT_F32)
          ((float*)Cp)[(size_t)(row0 + r) * N + col] = v;
        else
          ((short*)Cp)[(size_t)(row0 + r) * N + col] = bf16r(v);
      }
    }
  }
}

// ---------------- flash attention, 4-warp x 2 q-blocks, swapped-QK^T ----------------
// Q pre-scaled by SCALE*log2e. Scores provably bounded (|S|<~18<<127), so softmax
// uses FIXED m=0: no max-reduce, no rescale, no subtract. l accumulated per lane.
// Per block: 256 q-rows (4 warps x 64), KVBLK=64. K/V frags in LDS read ONCE per
// wave per kt and reused by both q-blocks (DS-per-MFMA halved vs R3).
__global__ __launch_bounds__(256, 2) void k_attn(
    const short* __restrict__ Q, const short* __restrict__ Kg,
    const short* __restrict__ Vg, short* __restrict__ Op)
{
  constexpr int T = 2048;
  constexpr int NT = T / 64;

  // bijective XCD-chunked swizzle: 512 blocks, 64 per XCD = 8 bh x 8 q-chunks
  const int orig = blockIdx.x;
  const int wgid = (orig & 7) * 64 + (orig >> 3);
  const int bh = wgid >> 3;            // 0..63
  const int qc = wgid & 7;             // q-chunk of 256 rows
  const int b = bh >> 5, h = bh & 31;
  const int g = h >> 2;
  const int q0 = qc * 256;

  const int t = threadIdx.x;
  const int lane = t & 63;
  const int wid = t >> 6;              // 0..3
  const int lo = lane & 31;
  const int hi = lane >> 5;

  __shared__ alignas(16) union {
    struct {
      short Kl[2][64 * 64];   // [key][d], XOR-swizzled, gload_lds staged
      short Vt[2][64 * 64];   // [d][key], XOR-swizzled, reg-staged transpose
    } s;
    short Ol[4][32 * 72];     // epilogue O transpose, per-warp
  } sm;

  // Q fragments (B-operand) for two 32-row q-blocks
  const size_t qrowA = (size_t)(b * T + q0 + wid * 64 + lo);
  short8 qfA[4], qfB[4];
  #pragma unroll
  for (int s = 0; s < 4; ++s) {
    qfA[s] = *reinterpret_cast<const short8*>(Q + qrowA * 2048 + h * 64 + s * 16 + hi * 8);
    qfB[s] = *reinterpret_cast<const short8*>(Q + (qrowA + 32) * 2048 + h * 64 + s * 16 + hi * 8);
  }

  f32x16 z16;
  #pragma unroll
  for (int r = 0; r < 16; ++r) z16[r] = 0.f;
  f32x16 oA0 = z16, oA1 = z16, oB0 = z16, oB1 = z16;
  float lA = 0.f, lB = 0.f;

  const short* Kbase = Kg + (size_t)(b * T) * 512 + g * 64;
  const short* Vbase = Vg + (size_t)(b * T) * 512 + g * 64;

  auto stageK = [&](int buf, int k0) {
    #pragma unroll
    for (int i = 0; i < 2; ++i) {
      int lin = (i * 256 + t) * 16;                // linear LDS byte dest
      int a = lin ^ (((lin >> 7) & 7) << 4);       // inverse-swizzled logical src
      int row = a >> 7;
      int col = (a & 127) >> 1;
      gload_lds16(Kbase + (size_t)(k0 + row) * 512 + col,
                  (char*)(&sm.s.Kl[buf][0]) + (wid << 10) + (i << 12));
    }
  };
  short8 vreg[2];
  auto loadV = [&](int k0) {
    const int d0 = (wid * 2 + hi) * 8;
    const size_t base = (size_t)(k0 + 2 * lo) * 512 + d0;
    vreg[0] = *reinterpret_cast<const short8*>(Vbase + base);
    vreg[1] = *reinterpret_cast<const short8*>(Vbase + base + 512);
  };
  auto writeV = [&](int buf) {
    const int d0 = (wid * 2 + hi) * 8;
    #pragma unroll
    for (int e = 0; e < 8; ++e) {
      int d = d0 + e;
      int byte = ((d << 7) + (lo << 2)) ^ ((d & 7) << 4);
      short2 pr; pr.x = vreg[0][e]; pr.y = vreg[1][e];
      *reinterpret_cast<short2*>((char*)(&sm.s.Vt[buf][0]) + byte) = pr;
    }
  };

  // softmax (fixed m=0) + P->bf16 B-frag pack with minimal cross-half exchange
  auto softmax_pb = [&](f32x16& st0, f32x16& st1, float& lacc, short8 (&pb)[4]) {
    #pragma unroll
    for (int r = 0; r < 16; ++r) st0[r] = fexp2(st0[r]);
    #pragma unroll
    for (int r = 0; r < 16; ++r) st1[r] = fexp2(st1[r]);
    float s01 = (((st0[0] + st0[1]) + (st0[2] + st0[3])) +
                 ((st0[4] + st0[5]) + (st0[6] + st0[7]))) +
                (((st0[8] + st0[9]) + (st0[10] + st0[11])) +
                 ((st0[12] + st0[13]) + (st0[14] + st0[15])));
    float s02 = (((st1[0] + st1[1]) + (st1[2] + st1[3])) +
                 ((st1[4] + st1[5]) + (st1[6] + st1[7]))) +
                (((st1[8] + st1[9]) + (st1[10] + st1[11])) +
                 ((st1[12] + st1[13]) + (st1[14] + st1[15])));
    float s = s01 + s02;
    s += __shfl_xor(s, 32);
    lacc += s;
    #pragma unroll
    for (int tt = 0; tt < 2; ++tt) {
      const f32x16& sv = tt ? st1 : st0;
      #pragma unroll
      for (int half = 0; half < 2; ++half) {
        unsigned x1 = cvtpk(sv[half * 8 + 0], sv[half * 8 + 1]);
        unsigned x2 = cvtpk(sv[half * 8 + 2], sv[half * 8 + 3]);
        unsigned x3 = cvtpk(sv[half * 8 + 4], sv[half * 8 + 5]);
        unsigned x4 = cvtpk(sv[half * 8 + 6], sv[half * 8 + 7]);
        unsigned t1 = hi ? x1 : x3, t2 = hi ? x2 : x4;   // what this half sends
        unsigned r1 = __shfl_xor(t1, 32), r2 = __shfl_xor(t2, 32);
        union { unsigned u[4]; short8 s8; } p;
        p.u[0] = hi ? r1 : x1;
        p.u[1] = hi ? r2 : x2;
        p.u[2] = hi ? x3 : r1;
        p.u[3] = hi ? x4 : r2;
        pb[tt * 2 + half] = p.s8;
      }
    }
  };

  stageK(0, 0);
  loadV(0);
  writeV(0);
  __syncthreads();

  int cur = 0;
  for (int kt = 0; kt < NT; ++kt) {
    const bool pf = (kt + 1 < NT);
    if (pf) { stageK(cur ^ 1, (kt + 1) * 64); loadV((kt + 1) * 64); }

    // ---- K frags (A-operand), read once, reused by both q-blocks ----
    short8 kf[2][4];
    #pragma unroll
    for (int tt = 0; tt < 2; ++tt)
      #pragma unroll
      for (int s = 0; s < 4; ++s) {
        int row = tt * 32 + lo;
        int byte = ((row << 7) + (s << 5) + (hi << 4)) ^ ((row & 7) << 4);
        kf[tt][s] = *reinterpret_cast<const short8*>((const char*)(&sm.s.Kl[cur][0]) + byte);
      }

    // ---- QK^T + softmax, q-block A ----
    __builtin_amdgcn_s_setprio(1);
    f32x16 s0 = mfma32(kf[0][0], qfA[0], z16);
    f32x16 s1 = mfma32(kf[1][0], qfA[0], z16);
    #pragma unroll
    for (int s = 1; s < 4; ++s) {
      s0 = mfma32(kf[0][s], qfA[s], s0);
      s1 = mfma32(kf[1][s], qfA[s], s1);
    }
    __builtin_amdgcn_s_setprio(0);
    short8 pbA[4];
    softmax_pb(s0, s1, lA, pbA);

    // ---- QK^T + softmax, q-block B ----
    __builtin_amdgcn_s_setprio(1);
    s0 = mfma32(kf[0][0], qfB[0], z16);
    s1 = mfma32(kf[1][0], qfB[0], z16);
    #pragma unroll
    for (int s = 1; s < 4; ++s) {
      s0 = mfma32(kf[0][s], qfB[s], s0);
      s1 = mfma32(kf[1][s], qfB[s], s1);
    }
    __builtin_amdgcn_s_setprio(0);
    short8 pbB[4];
    softmax_pb(s0, s1, lB, pbB);

    // ---- PV: V^T frags read once, reused by both q-blocks ----
    __builtin_amdgcn_s_setprio(1);
    #pragma unroll
    for (int ks = 0; ks < 4; ++ks) {
      int cb = (ks * 16 + hi * 8) << 1;
      short8 vlo = *reinterpret_cast<const short8*>(
          (const char*)(&sm.s.Vt[cur][0]) + (((lo << 7) + cb) ^ ((lo & 7) << 4)));
      oA0 = mfma32(vlo, pbA[ks], oA0);
      oB0 = mfma32(vlo, pbB[ks], oB0);
      short8 vhi = *reinterpret_cast<const short8*>(
          (const char*)(&sm.s.Vt[cur][0]) + ((((32 + lo) << 7) + cb) ^ ((lo & 7) << 4)));
      oA1 = mfma32(vhi, pbA[ks], oA1);
      oB1 = mfma32(vhi, pbB[ks], oB1);
    }
    __builtin_amdgcn_s_setprio(0);

    if (pf) writeV(cur ^ 1);
    __syncthreads();
    cur ^= 1;
  }

  // ---- epilogue: normalize, transpose via per-warp LDS, store ----
  auto store_o = [&](const f32x16& o0v, const f32x16& o1v, float inv, size_t qrow) {
    #pragma unroll
    for (int dt = 0; dt < 2; ++dt) {
      const f32x16& ov = dt ? o1v : o0v;
      #pragma unroll
      for (int r = 0; r < 16; r += 2) {
        unsigned d2 = cvtpk(ov[r] * inv, ov[r + 1] * inv);
        int dpos = dt * 32 + (r & 3) + 8 * (r >> 2) + 4 * hi;
        *reinterpret_cast<unsigned*>((char*)(&sm.Ol[wid][0]) + (lo * 72 + dpos) * 2) = d2;
      }
    }
    #pragma unroll
    for (int i = 0; i < 4; ++i) {
      int c = hi * 4 + i;
      short8 v = *reinterpret_cast<const short8*>((const char*)(&sm.Ol[wid][0]) + lo * 144 + c * 16);
      *reinterpret_cast<short8*>(Op + qrow * 2048 + h * 64 + c * 8) = v;
    }
  };
  // loop-end __syncthreads() already separated Vt reads from Ol alias reuse
  store_o(oA0, oA1, 1.0f / lA, qrowA);
  store_o(oB0, oB1, 1.0f / lB, qrowA + 32);
}

// ---------------- launch ----------------
extern "C" void kernel_launch(void* const* d_in, const int* in_sizes, int n_in,
                              void* d_out, int out_size, void* d_ws, size_t ws_size,
                              hipStream_t stream)
{
  const float* query = (const float*)d_in[0];
  const float* key   = (const float*)d_in[1];
  const float* value = (const float*)d_in[2];
  const float* q_w   = (const float*)d_in[3];
  const float* q_b   = (const float*)d_in[4];
  const float* k_w   = (const float*)d_in[5];
  const float* k_b   = (const float*)d_in[6];
  const float* v_w   = (const float*)d_in[7];
  const float* v_b   = (const float*)d_in[8];
  const float* o_w   = (const float*)d_in[9];
  const float* o_b   = (const float*)d_in[10];
  float* out = (float*)d_out;

  char* ws = (char*)d_ws;
  short* q_wb = (short*)(ws);                  // 8388608 B
  short* k_wb = (short*)(ws + 8388608);        // 2097152
  short* v_wb = (short*)(ws + 10485760);       // 2097152
  short* o_wb = (short*)(ws + 12582912);       // 8388608
  short* Qp   = (short*)(ws + 20971520);       // 16777216
  short* Kp   = (short*)(ws + 37748736);       // 4194304
  short* Vp   = (short*)(ws + 41943040);       // 4194304
  short* Ap   = (short*)(ws + 46137344);       // 16777216

  k_cvt<<<4096, 256, 0, stream>>>(q_w, q_wb, 1048576);
  k_cvt<<<1024, 256, 0, stream>>>(k_w, k_wb, 262144);
  k_cvt<<<1024, 256, 0, stream>>>(v_w, v_wb, 262144);
  k_cvt<<<4096, 256, 0, stream>>>(o_w, o_wb, 1048576);

  // fold SCALE (0.125) and log2(e) into Q so softmax runs in exp2 domain
  const float ALPHA_Q = 0.125f * 1.4426950408889634f;

  k_gemm<true, false, false><<<dim3(16, 32), 256, 0, stream>>>(
      query, q_wb, q_b, Qp, nullptr, nullptr, nullptr, nullptr, 4096, 2048, 2048, ALPHA_Q);
  // fused K-proj / V-proj (z selects)
  k_gemm<true, false, true><<<dim3(4, 32, 2), 256, 0, stream>>>(
      key, k_wb, k_b, Kp, value, v_wb, v_b, Vp, 4096, 512, 2048, 1.0f);

  k_attn<<<dim3(512), dim3(256), 0, stream>>>(Qp, Kp, Vp, Ap);

  k_gemm<false, true, false><<<dim3(16, 32), 256, 0, stream>>>(
      Ap, o_wb, o_b, out, nullptr, nullptr, nullptr, nullptr, 4096, 2048, 2048, 1.0f);
}

// Round 8
// 296.186 us; speedup vs baseline: 1.1552x; 1.1552x over previous
//
#include <hip/hip_runtime.h>
#include <stdint.h>
#include <stddef.h>

using short8 = __attribute__((ext_vector_type(8))) short;
using short4v = __attribute__((ext_vector_type(4))) short;
using f32x4  = __attribute__((ext_vector_type(4))) float;
using f32x16 = __attribute__((ext_vector_type(16))) float;
using bf16x8 = __attribute__((ext_vector_type(8))) __bf16;

#define DEVI __device__ __forceinline__

// round-to-nearest-even fp32 -> bf16 (bit pattern as short)
DEVI short bf16r(float f) {
  union { float f; uint32_t u; } x; x.f = f;
  uint32_t r = x.u + 0x7FFFu + ((x.u >> 16) & 1u);
  return (short)(r >> 16);
}

DEVI f32x4 mfma16(short8 a, short8 b, f32x4 c) {
  return __builtin_amdgcn_mfma_f32_16x16x32_bf16(
      __builtin_bit_cast(bf16x8, a), __builtin_bit_cast(bf16x8, b), c, 0, 0, 0);
}

DEVI f32x16 mfma32(short8 a, short8 b, f32x16 c) {
  return __builtin_amdgcn_mfma_f32_32x32x16_bf16(
      __builtin_bit_cast(bf16x8, a), __builtin_bit_cast(bf16x8, b), c, 0, 0, 0);
}

DEVI void gload_lds16(const void* g, void* l) {
  __builtin_amdgcn_global_load_lds(
      (const void __attribute__((address_space(1)))*)g,
      (void __attribute__((address_space(3)))*)l,
      16, 0, 0);
}

// v_exp_f32 computes 2^x
DEVI float fexp2(float x) {
  float r;
  asm("v_exp_f32 %0, %1" : "=v"(r) : "v"(x));
  return r;
}

// packed fp32->bf16: dst[15:0]=bf16(a), dst[31:16]=bf16(b)
DEVI unsigned cvtpk(float a, float b) {
  unsigned r;
  asm("v_cvt_pk_bf16_f32 %0, %1, %2" : "=v"(r) : "v"(a), "v"(b));
  return r;
}

// ---------------- fp32 -> bf16 conversion (weights) ----------------
__global__ void k_cvt(const float* __restrict__ src, short* __restrict__ dst, int n4) {
  int i = blockIdx.x * blockDim.x + threadIdx.x;
  if (i < n4) {
    f32x4 v = reinterpret_cast<const f32x4*>(src)[i];
    short4v o;
    o[0] = bf16r(v[0]); o[1] = bf16r(v[1]); o[2] = bf16r(v[2]); o[3] = bf16r(v[3]);
    reinterpret_cast<short4v*>(dst)[i] = o;
  }
}

// ---------------- GEMM: C(M,N) = (A(M,K) @ W(N,K)^T + bias) * alpha ----------------
// DUAL: blockIdx.z selects {Ap,Bw,bias,Cp} vs {Ap2,Bw2,bias2,Cp2} (fuses K/V proj)
template<bool A_F32, bool OUT_F32, bool DUAL>
__global__ __launch_bounds__(256) void k_gemm(
    const void* __restrict__ Ap, const short* __restrict__ Bw,
    const float* __restrict__ bias, void* __restrict__ Cp,
    const void* __restrict__ Ap2, const short* __restrict__ Bw2,
    const float* __restrict__ bias2, void* __restrict__ Cp2,
    int M, int N, int K, float alpha)
{
  if constexpr (DUAL) {
    if (blockIdx.z) { Ap = Ap2; Bw = Bw2; bias = bias2; Cp = Cp2; }
  }
  __shared__ short As[2][128 * 64];
  __shared__ short Bs[2][128 * 64];
  const int t = threadIdx.x;
  const int lane = t & 63;
  const int wid = t >> 6;
  const int wr = wid >> 1, wc = wid & 1;
  const int bm = blockIdx.y * 128;
  const int bn = blockIdx.x * 128;

  f32x4 acc[4][4];
  #pragma unroll
  for (int i = 0; i < 4; ++i)
    #pragma unroll
    for (int j = 0; j < 4; ++j) acc[i][j] = f32x4{0.f, 0.f, 0.f, 0.f};

  const int nt = K >> 6;

  auto stageB = [&](int buf, int k0) {
    #pragma unroll
    for (int i = 0; i < 4; ++i) {
      int lin = t * 16 + i * 4096;
      int a = lin ^ (((lin >> 7) & 7) << 4);
      int row = a >> 7;
      int col = (a & 127) >> 1;
      const short* g = Bw + (size_t)(bn + row) * K + k0 + col;
      gload_lds16(g, (char*)(&Bs[buf][0]) + (wid << 10) + (i << 12));
    }
  };
  auto stageA_bf16 = [&](int buf, int k0) {
    const short* A = (const short*)Ap;
    #pragma unroll
    for (int i = 0; i < 4; ++i) {
      int lin = t * 16 + i * 4096;
      int a = lin ^ (((lin >> 7) & 7) << 4);
      int row = a >> 7;
      int col = (a & 127) >> 1;
      const short* g = A + (size_t)(bm + row) * K + k0 + col;
      gload_lds16(g, (char*)(&As[buf][0]) + (wid << 10) + (i << 12));
    }
  };
  auto loadA_f32 = [&](int k0, float (&r)[4][8]) {
    const float* A = (const float*)Ap;
    #pragma unroll
    for (int i = 0; i < 4; ++i) {
      int idx = (t + i * 256) * 8;
      int row = idx >> 6;
      int col = idx & 63;
      const float* g = A + (size_t)(bm + row) * K + k0 + col;
      f32x4 v0 = *reinterpret_cast<const f32x4*>(g);
      f32x4 v1 = *reinterpret_cast<const f32x4*>(g + 4);
      r[i][0] = v0[0]; r[i][1] = v0[1]; r[i][2] = v0[2]; r[i][3] = v0[3];
      r[i][4] = v1[0]; r[i][5] = v1[1]; r[i][6] = v1[2]; r[i][7] = v1[3];
    }
  };
  auto writeA_f32 = [&](int buf, float (&r)[4][8]) {
    #pragma unroll
    for (int i = 0; i < 4; ++i) {
      int idx = (t + i * 256) * 8;
      int row = idx >> 6;
      int col = idx & 63;
      short8 s;
      #pragma unroll
      for (int e = 0; e < 8; ++e) s[e] = bf16r(r[i][e]);
      int byte = ((row << 7) + (col << 1)) ^ ((row & 7) << 4);
      *reinterpret_cast<short8*>((char*)(&As[buf][0]) + byte) = s;
    }
  };

  if constexpr (A_F32) {
    float r0[4][8];
    loadA_f32(0, r0);
    writeA_f32(0, r0);
  } else {
    stageA_bf16(0, 0);
  }
  stageB(0, 0);
  __syncthreads();

  int cur = 0;
  for (int kt = 0; kt < nt; ++kt) {
    float ra[4][8];
    const bool pf = (kt + 1 < nt);
    if (pf) {
      if constexpr (A_F32) loadA_f32((kt + 1) << 6, ra);
      else stageA_bf16(cur ^ 1, (kt + 1) << 6);
      stageB(cur ^ 1, (kt + 1) << 6);
    }
    #pragma unroll
    for (int kk = 0; kk < 2; ++kk) {
      const int kb = (kk * 32 + ((lane >> 4) << 3)) << 1;
      short8 af[4], bfr[4];
      #pragma unroll
      for (int i = 0; i < 4; ++i) {
        int row = wr * 64 + i * 16 + (lane & 15);
        int byte = ((row << 7) + kb) ^ ((row & 7) << 4);
        af[i] = *reinterpret_cast<const short8*>((const char*)(&As[cur][0]) + byte);
      }
      #pragma unroll
      for (int j = 0; j < 4; ++j) {
        int row = wc * 64 + j * 16 + (lane & 15);
        int byte = ((row << 7) + kb) ^ ((row & 7) << 4);
        bfr[j] = *reinterpret_cast<const short8*>((const char*)(&Bs[cur][0]) + byte);
      }
      #pragma unroll
      for (int i = 0; i < 4; ++i)
        #pragma unroll
        for (int j = 0; j < 4; ++j)
          acc[i][j] = mfma16(af[i], bfr[j], acc[i][j]);
    }
    if constexpr (A_F32) {
      if (pf) writeA_f32(cur ^ 1, ra);
    }
    __syncthreads();
    cur ^= 1;
  }

  #pragma unroll
  for (int j = 0; j < 4; ++j) {
    int col = bn + wc * 64 + j * 16 + (lane & 15);
    float bv = bias[col];
    #pragma unroll
    for (int i = 0; i < 4; ++i) {
      int row0 = bm + wr * 64 + i * 16 + ((lane >> 4) << 2);
      #pragma unroll
      for (int r = 0; r < 4; ++r) {
        float v = (acc[i][j][r] + bv) * alpha;
        if constexpr (OUT_F32)
          ((float*)Cp)[(size_t)(row0 + r) * N + col] = v;
        else
          ((short*)Cp)[(size_t)(row0 + r) * N + col] = bf16r(v);
      }
    }
  }
}

// ---------------- flash attention, 8-warp swapped-QK^T (R3 VERBATIM — green) ----------------
// Q: (B,T,H*64) bf16 pre-scaled by SCALE*log2e. K/V: (B,T,G*64) bf16. O: (B,T,H*64) bf16.
// Per block: 256 q-rows (8 warps x 32), KVBLK=64, 32x32x16 MFMA.
// S^T = mfma(K, Q): col=q=lane&31 -> lane-local softmax state (m,l).
// NOTE: fixed-m=0 softmax in THIS structure fails (R5/R6/R7, absmax ~0.04,
// mechanism unknown) while passing in the 4-warp structure (R4). Defer-max
// (T13) is the proven-green form here — do not swap without a new theory.
__global__ __launch_bounds__(512) void k_attn(
    const short* __restrict__ Q, const short* __restrict__ Kg,
    const short* __restrict__ Vg, short* __restrict__ Op)
{
  constexpr int T = 2048;
  constexpr int NT = T / 64;

  // bijective XCD-chunked swizzle: 512 blocks -> 64 contiguous per XCD
  const int orig = blockIdx.x;
  const int wgid = (orig & 7) * 64 + (orig >> 3);
  const int bh = wgid >> 3;            // 0..63 = b*32+h
  const int qb = wgid & 7;
  const int b = bh >> 5, h = bh & 31;
  const int g = h >> 2;
  const int q0 = qb * 256;

  const int t = threadIdx.x;
  const int lane = t & 63;
  const int wid = t >> 6;
  const int lo = lane & 31;
  const int hi = lane >> 5;

  __shared__ alignas(16) union {
    struct {
      short Kl[2][64 * 64];   // [key][d], XOR-swizzled bytes, gload_lds staged
      short Vt[2][64 * 72];   // [d][key], stride 72, reg-staged transpose
    } s;
    short Ol[8][32 * 72];     // epilogue O transpose, per-warp
  } sm;

  // Q fragments (B-operand): lane holds Q[q0w+lo][s*16 + hi*8 .. +8]
  const size_t qrow = (size_t)(b * T + q0 + wid * 32 + lo);
  short8 qf[4];
  #pragma unroll
  for (int s = 0; s < 4; ++s)
    qf[s] = *reinterpret_cast<const short8*>(Q + qrow * 2048 + h * 64 + s * 16 + hi * 8);

  f32x16 o0, o1;
  #pragma unroll
  for (int r = 0; r < 16; ++r) { o0[r] = 0.f; o1[r] = 0.f; }
  float m = -10000.f, l = 0.f;

  const short* Kbase = Kg + (size_t)(b * T) * 512 + g * 64;
  const short* Vbase = Vg + (size_t)(b * T) * 512 + g * 64;

  auto stageK = [&](int buf, int k0) {
    int lin = t * 16;                            // linear LDS byte dest
    int a = lin ^ (((lin >> 7) & 7) << 4);       // inverse-swizzled logical src
    int row = a >> 7;
    int col = (a & 127) >> 1;
    gload_lds16(Kbase + (size_t)(k0 + row) * 512 + col,
                (char*)(&sm.s.Kl[buf][0]) + (wid << 10));
  };
  short8 vreg;
  auto loadV = [&](int k0) {
    // thread t: key=lane, d-chunk=wid*8 (16B per lane)
    vreg = *reinterpret_cast<const short8*>(
        Vbase + (size_t)(k0 + lane) * 512 + wid * 8);
  };
  auto writeV = [&](int buf) {
    // V^T[d][key]: lanes write consecutive keys -> conflict-free
    #pragma unroll
    for (int e = 0; e < 8; ++e)
      sm.s.Vt[buf][(wid * 8 + e) * 72 + lane] = vreg[e];
  };

  stageK(0, 0);
  loadV(0);
  writeV(0);
  __syncthreads();

  int cur = 0;
  for (int kt = 0; kt < NT; ++kt) {
    const bool pf = (kt + 1 < NT);
    if (pf) { stageK(cur ^ 1, (kt + 1) * 64); loadV((kt + 1) * 64); }

    // ---- K frags (A-operand) + QK^T ----
    short8 kf[2][4];
    #pragma unroll
    for (int tt = 0; tt < 2; ++tt)
      #pragma unroll
      for (int s = 0; s < 4; ++s) {
        int row = tt * 32 + lo;
        int byte = ((row << 7) + (s << 5) + (hi << 4)) ^ ((row & 7) << 4);
        kf[tt][s] = *reinterpret_cast<const short8*>((const char*)(&sm.s.Kl[cur][0]) + byte);
      }
    f32x16 st0, st1;
    #pragma unroll
    for (int r = 0; r < 16; ++r) { st0[r] = 0.f; st1[r] = 0.f; }
    #pragma unroll
    for (int s = 0; s < 4; ++s) {
      st0 = mfma32(kf[0][s], qf[s], st0);
      st1 = mfma32(kf[1][s], qf[s], st1);
    }

    // ---- online softmax (log2 domain), lane-local q ----
    float mx = st0[0];
    #pragma unroll
    for (int r = 1; r < 16; ++r) mx = fmaxf(mx, st0[r]);
    #pragma unroll
    for (int r = 0; r < 16; ++r) mx = fmaxf(mx, st1[r]);
    mx = fmaxf(mx, __shfl_xor(mx, 32));
    if (!__all(mx - m <= 8.0f)) {      // T13 defer-max
      float mn = fmaxf(m, mx);
      float sc = fexp2(m - mn);
      m = mn; l *= sc;
      o0 = o0 * sc; o1 = o1 * sc;
    }
    float ssum = 0.f;
    #pragma unroll
    for (int r = 0; r < 16; ++r) { float e = fexp2(st0[r] - m); st0[r] = e; ssum += e; }
    #pragma unroll
    for (int r = 0; r < 16; ++r) { float e = fexp2(st1[r] - m); st1[r] = e; ssum += e; }
    ssum += __shfl_xor(ssum, 32);
    l += ssum;

    // ---- P -> bf16 B-frags: cvt_pk + cross-half shfl_xor redistribution ----
    // target B-frag word w of pb[ks]: keys ks*16 + hi*8 + 2w, +2w+1 @ q=lo
    short8 pb[4];
    #pragma unroll
    for (int tt = 0; tt < 2; ++tt) {
      const f32x16& sv = tt ? st1 : st0;
      #pragma unroll
      for (int half = 0; half < 2; ++half) {
        unsigned x1 = cvtpk(sv[half * 8 + 0], sv[half * 8 + 1]);   // keys +0,+1 (+4hi)
        unsigned x2 = cvtpk(sv[half * 8 + 2], sv[half * 8 + 3]);   // keys +2,+3
        unsigned x3 = cvtpk(sv[half * 8 + 4], sv[half * 8 + 5]);   // keys +8,+9
        unsigned x4 = cvtpk(sv[half * 8 + 6], sv[half * 8 + 7]);   // keys +10,+11
        unsigned y1 = __shfl_xor(x1, 32);
        unsigned y2 = __shfl_xor(x2, 32);
        unsigned y3 = __shfl_xor(x3, 32);
        unsigned y4 = __shfl_xor(x4, 32);
        union { unsigned u[4]; short8 s8; } p;
        p.u[0] = hi ? y3 : x1;   // w0: keys +8hi+0,1
        p.u[1] = hi ? y4 : x2;   // w1: keys +8hi+2,3
        p.u[2] = hi ? x3 : y1;   // w2: keys +8hi+4,5
        p.u[3] = hi ? x4 : y2;   // w3: keys +8hi+6,7
        pb[tt * 2 + half] = p.s8;
      }
    }

    // ---- V^T frags (A-operand) + PV ----
    #pragma unroll
    for (int ks = 0; ks < 4; ++ks) {
      {
        int byte = (lo * 144) + (ks << 5) + (hi << 4);
        short8 va = *reinterpret_cast<const short8*>((const char*)(&sm.s.Vt[cur][0]) + byte);
        o0 = mfma32(va, pb[ks], o0);
      }
      {
        int byte = ((32 + lo) * 144) + (ks << 5) + (hi << 4);
        short8 va = *reinterpret_cast<const short8*>((const char*)(&sm.s.Vt[cur][0]) + byte);
        o1 = mfma32(va, pb[ks], o1);
      }
    }

    if (pf) writeV(cur ^ 1);
    __syncthreads();
    cur ^= 1;
  }

  // ---- epilogue: normalize, transpose via LDS, coalesced store ----
  float inv = 1.0f / l;
  #pragma unroll
  for (int dt = 0; dt < 2; ++dt) {
    const f32x16& ov = dt ? o1 : o0;
    #pragma unroll
    for (int r = 0; r < 16; r += 2) {
      unsigned d2 = cvtpk(ov[r] * inv, ov[r + 1] * inv);
      int dpos = dt * 32 + (r & 3) + 8 * (r >> 2) + 4 * hi;   // even
      *reinterpret_cast<unsigned*>((char*)(&sm.Ol[wid][0]) + (lo * 72 + dpos) * 2) = d2;
    }
  }
  __syncthreads();
  #pragma unroll
  for (int i = 0; i < 4; ++i) {
    int c = hi * 4 + i;
    short8 v = *reinterpret_cast<const short8*>((const char*)(&sm.Ol[wid][0]) + lo * 144 + c * 16);
    *reinterpret_cast<short8*>(Op + qrow * 2048 + h * 64 + c * 8) = v;
  }
}

// ---------------- launch (R4's verified dataflow, no aliasing) ----------------
extern "C" void kernel_launch(void* const* d_in, const int* in_sizes, int n_in,
                              void* d_out, int out_size, void* d_ws, size_t ws_size,
                              hipStream_t stream)
{
  const float* query = (const float*)d_in[0];
  const float* key   = (const float*)d_in[1];
  const float* value = (const float*)d_in[2];
  const float* q_w   = (const float*)d_in[3];
  const float* q_b   = (const float*)d_in[4];
  const float* k_w   = (const float*)d_in[5];
  const float* k_b   = (const float*)d_in[6];
  const float* v_w   = (const float*)d_in[7];
  const float* v_b   = (const float*)d_in[8];
  const float* o_w   = (const float*)d_in[9];
  const float* o_b   = (const float*)d_in[10];
  float* out = (float*)d_out;

  char* ws = (char*)d_ws;
  short* q_wb = (short*)(ws);                  // 8388608 B
  short* k_wb = (short*)(ws + 8388608);        // 2097152
  short* v_wb = (short*)(ws + 10485760);       // 2097152
  short* o_wb = (short*)(ws + 12582912);       // 8388608
  short* Qp   = (short*)(ws + 20971520);       // 16777216
  short* Kp   = (short*)(ws + 37748736);       // 4194304
  short* Vp   = (short*)(ws + 41943040);       // 4194304
  short* Ap   = (short*)(ws + 46137344);       // 16777216

  k_cvt<<<4096, 256, 0, stream>>>(q_w, q_wb, 1048576);
  k_cvt<<<1024, 256, 0, stream>>>(k_w, k_wb, 262144);
  k_cvt<<<1024, 256, 0, stream>>>(v_w, v_wb, 262144);
  k_cvt<<<4096, 256, 0, stream>>>(o_w, o_wb, 1048576);

  // fold SCALE (0.125) and log2(e) into Q so softmax runs in exp2 domain
  const float ALPHA_Q = 0.125f * 1.4426950408889634f;

  k_gemm<true, false, false><<<dim3(16, 32), 256, 0, stream>>>(
      query, q_wb, q_b, Qp, nullptr, nullptr, nullptr, nullptr, 4096, 2048, 2048, ALPHA_Q);
  // fused K-proj / V-proj (z selects)
  k_gemm<true, false, true><<<dim3(4, 32, 2), 256, 0, stream>>>(
      key, k_wb, k_b, Kp, value, v_wb, v_b, Vp, 4096, 512, 2048, 1.0f);

  k_attn<<<dim3(512), dim3(512), 0, stream>>>(Qp, Kp, Vp, Ap);

  k_gemm<false, true, false><<<dim3(16, 32), 256, 0, stream>>>(
      Ap, o_wb, o_b, out, nullptr, nullptr, nullptr, nullptr, 4096, 2048, 2048, 1.0f);
}

// Round 9
// 257.620 us; speedup vs baseline: 1.3282x; 1.1497x over previous
//
#include <hip/hip_runtime.h>
#include <stdint.h>
#include <stddef.h>

using short8 = __attribute__((ext_vector_type(8))) short;
using short4v = __attribute__((ext_vector_type(4))) short;
using f32x4  = __attribute__((ext_vector_type(4))) float;
using f32x16 = __attribute__((ext_vector_type(16))) float;
using bf16x8 = __attribute__((ext_vector_type(8))) __bf16;

#define DEVI __device__ __forceinline__

// round-to-nearest-even fp32 -> bf16 (bit pattern as short)
DEVI short bf16r(float f) {
  union { float f; uint32_t u; } x; x.f = f;
  uint32_t r = x.u + 0x7FFFu + ((x.u >> 16) & 1u);
  return (short)(r >> 16);
}

DEVI f32x4 mfma16(short8 a, short8 b, f32x4 c) {
  return __builtin_amdgcn_mfma_f32_16x16x32_bf16(
      __builtin_bit_cast(bf16x8, a), __builtin_bit_cast(bf16x8, b), c, 0, 0, 0);
}

DEVI f32x16 mfma32(short8 a, short8 b, f32x16 c) {
  return __builtin_amdgcn_mfma_f32_32x32x16_bf16(
      __builtin_bit_cast(bf16x8, a), __builtin_bit_cast(bf16x8, b), c, 0, 0, 0);
}

DEVI void gload_lds16(const void* g, void* l) {
  __builtin_amdgcn_global_load_lds(
      (const void __attribute__((address_space(1)))*)g,
      (void __attribute__((address_space(3)))*)l,
      16, 0, 0);
}

// v_exp_f32 computes 2^x
DEVI float fexp2(float x) {
  float r;
  asm("v_exp_f32 %0, %1" : "=v"(r) : "v"(x));
  return r;
}

// packed fp32->bf16: dst[15:0]=bf16(a), dst[31:16]=bf16(b)
DEVI unsigned cvtpk(float a, float b) {
  unsigned r;
  asm("v_cvt_pk_bf16_f32 %0, %1, %2" : "=v"(r) : "v"(a), "v"(b));
  return r;
}

// ---------------- fp32 -> bf16 conversion (dual-segment: z selects) ----------------
__global__ void k_cvt2(const float* __restrict__ s0, short* __restrict__ d0,
                       const float* __restrict__ s1, short* __restrict__ d1, int n4) {
  const float* s = blockIdx.z ? s1 : s0;
  short* d = blockIdx.z ? d1 : d0;
  int i = blockIdx.x * blockDim.x + threadIdx.x;
  if (i < n4) {
    f32x4 v = reinterpret_cast<const f32x4*>(s)[i];
    short4v o;
    o[0] = bf16r(v[0]); o[1] = bf16r(v[1]); o[2] = bf16r(v[2]); o[3] = bf16r(v[3]);
    reinterpret_cast<short4v*>(d)[i] = o;
  }
}

__global__ void k_cvt(const float* __restrict__ src, short* __restrict__ dst, int n4) {
  int i = blockIdx.x * blockDim.x + threadIdx.x;
  if (i < n4) {
    f32x4 v = reinterpret_cast<const f32x4*>(src)[i];
    short4v o;
    o[0] = bf16r(v[0]); o[1] = bf16r(v[1]); o[2] = bf16r(v[2]); o[3] = bf16r(v[3]);
    reinterpret_cast<short4v*>(dst)[i] = o;
  }
}

// ---------------- GEMM: C(M,N) = (A(M,K)bf16 @ W(N,K)^T + bias) * alpha ----------------
// Both operands staged via global_load_lds w=16, XOR-swizzled both-sides (m97 path).
// DUAL: blockIdx.z selects a second {A,B,bias,C} set (fuses K-proj/V-proj).
// [R5's kernel, green-validated by R5==R6 absmax equality]
template<bool OUT_F32, bool DUAL>
__global__ __launch_bounds__(256) void k_gemm(
    const short* __restrict__ Aw, const short* __restrict__ Bw,
    const float* __restrict__ bias, void* __restrict__ Cp,
    const short* __restrict__ Aw2, const short* __restrict__ Bw2,
    const float* __restrict__ bias2, void* __restrict__ Cp2,
    int M, int N, int K, float alpha)
{
  if constexpr (DUAL) {
    if (blockIdx.z) { Aw = Aw2; Bw = Bw2; bias = bias2; Cp = Cp2; }
  }
  __shared__ short As[2][128 * 64];
  __shared__ short Bs[2][128 * 64];
  const int t = threadIdx.x;
  const int lane = t & 63;
  const int wid = t >> 6;
  const int wr = wid >> 1, wc = wid & 1;
  const int bm = blockIdx.y * 128;
  const int bn = blockIdx.x * 128;

  f32x4 acc[4][4];
  #pragma unroll
  for (int i = 0; i < 4; ++i)
    #pragma unroll
    for (int j = 0; j < 4; ++j) acc[i][j] = f32x4{0.f, 0.f, 0.f, 0.f};

  const int nt = K >> 6;

  auto stage = [&](const short* G, short (&buf)[128 * 64], int k0) {
    #pragma unroll
    for (int i = 0; i < 4; ++i) {
      int lin = t * 16 + i * 4096;
      int a = lin ^ (((lin >> 7) & 7) << 4);
      int row = a >> 7;
      int col = (a & 127) >> 1;
      const short* g = G + (size_t)row * K + k0 + col;
      gload_lds16(g, (char*)(&buf[0]) + (wid << 10) + (i << 12));
    }
  };

  stage(Aw + (size_t)bm * K, As[0], 0);
  stage(Bw + (size_t)bn * K, Bs[0], 0);
  __syncthreads();

  int cur = 0;
  for (int kt = 0; kt < nt; ++kt) {
    const bool pf = (kt + 1 < nt);
    if (pf) {
      stage(Aw + (size_t)bm * K, As[cur ^ 1], (kt + 1) << 6);
      stage(Bw + (size_t)bn * K, Bs[cur ^ 1], (kt + 1) << 6);
    }
    #pragma unroll
    for (int kk = 0; kk < 2; ++kk) {
      const int kb = (kk * 32 + ((lane >> 4) << 3)) << 1;
      short8 af[4], bfr[4];
      #pragma unroll
      for (int i = 0; i < 4; ++i) {
        int row = wr * 64 + i * 16 + (lane & 15);
        int byte = ((row << 7) + kb) ^ ((row & 7) << 4);
        af[i] = *reinterpret_cast<const short8*>((const char*)(&As[cur][0]) + byte);
      }
      #pragma unroll
      for (int j = 0; j < 4; ++j) {
        int row = wc * 64 + j * 16 + (lane & 15);
        int byte = ((row << 7) + kb) ^ ((row & 7) << 4);
        bfr[j] = *reinterpret_cast<const short8*>((const char*)(&Bs[cur][0]) + byte);
      }
      __builtin_amdgcn_s_setprio(1);
      #pragma unroll
      for (int i = 0; i < 4; ++i)
        #pragma unroll
        for (int j = 0; j < 4; ++j)
          acc[i][j] = mfma16(af[i], bfr[j], acc[i][j]);
      __builtin_amdgcn_s_setprio(0);
    }
    __syncthreads();
    cur ^= 1;
  }

  #pragma unroll
  for (int j = 0; j < 4; ++j) {
    int col = bn + wc * 64 + j * 16 + (lane & 15);
    float bv = bias[col];
    #pragma unroll
    for (int i = 0; i < 4; ++i) {
      int row0 = bm + wr * 64 + i * 16 + ((lane >> 4) << 2);
      #pragma unroll
      for (int r = 0; r < 4; ++r) {
        float v = (acc[i][j][r] + bv) * alpha;
        if constexpr (OUT_F32)
          ((float*)Cp)[(size_t)(row0 + r) * N + col] = v;
        else
          ((short*)Cp)[(size_t)(row0 + r) * N + col] = bf16r(v);
      }
    }
  }
}

// ---------------- flash attention, 8-warp swapped-QK^T (R3 VERBATIM — green) ----------------
// Q: (B,T,H*64) bf16 pre-scaled by SCALE*log2e. K/V: (B,T,G*64) bf16. O: (B,T,H*64) bf16.
// Per block: 256 q-rows (8 warps x 32), KVBLK=64, 32x32x16 MFMA.
// S^T = mfma(K, Q): col=q=lane&31 -> lane-local softmax state (m,l).
// NOTE: fixed-m=0 softmax in THIS structure fails (R5/R6/R7, absmax ~0.04,
// mechanism unknown) while passing in the 4-warp structure (R4). Defer-max
// (T13) is the proven-green form here — do not swap without a new theory.
__global__ __launch_bounds__(512) void k_attn(
    const short* __restrict__ Q, const short* __restrict__ Kg,
    const short* __restrict__ Vg, short* __restrict__ Op)
{
  constexpr int T = 2048;
  constexpr int NT = T / 64;

  // bijective XCD-chunked swizzle: 512 blocks -> 64 contiguous per XCD
  const int orig = blockIdx.x;
  const int wgid = (orig & 7) * 64 + (orig >> 3);
  const int bh = wgid >> 3;            // 0..63 = b*32+h
  const int qb = wgid & 7;
  const int b = bh >> 5, h = bh & 31;
  const int g = h >> 2;
  const int q0 = qb * 256;

  const int t = threadIdx.x;
  const int lane = t & 63;
  const int wid = t >> 6;
  const int lo = lane & 31;
  const int hi = lane >> 5;

  __shared__ alignas(16) union {
    struct {
      short Kl[2][64 * 64];   // [key][d], XOR-swizzled bytes, gload_lds staged
      short Vt[2][64 * 72];   // [d][key], stride 72, reg-staged transpose
    } s;
    short Ol[8][32 * 72];     // epilogue O transpose, per-warp
  } sm;

  // Q fragments (B-operand): lane holds Q[q0w+lo][s*16 + hi*8 .. +8]
  const size_t qrow = (size_t)(b * T + q0 + wid * 32 + lo);
  short8 qf[4];
  #pragma unroll
  for (int s = 0; s < 4; ++s)
    qf[s] = *reinterpret_cast<const short8*>(Q + qrow * 2048 + h * 64 + s * 16 + hi * 8);

  f32x16 o0, o1;
  #pragma unroll
  for (int r = 0; r < 16; ++r) { o0[r] = 0.f; o1[r] = 0.f; }
  float m = -10000.f, l = 0.f;

  const short* Kbase = Kg + (size_t)(b * T) * 512 + g * 64;
  const short* Vbase = Vg + (size_t)(b * T) * 512 + g * 64;

  auto stageK = [&](int buf, int k0) {
    int lin = t * 16;                            // linear LDS byte dest
    int a = lin ^ (((lin >> 7) & 7) << 4);       // inverse-swizzled logical src
    int row = a >> 7;
    int col = (a & 127) >> 1;
    gload_lds16(Kbase + (size_t)(k0 + row) * 512 + col,
                (char*)(&sm.s.Kl[buf][0]) + (wid << 10));
  };
  short8 vreg;
  auto loadV = [&](int k0) {
    // thread t: key=lane, d-chunk=wid*8 (16B per lane)
    vreg = *reinterpret_cast<const short8*>(
        Vbase + (size_t)(k0 + lane) * 512 + wid * 8);
  };
  auto writeV = [&](int buf) {
    // V^T[d][key]: lanes write consecutive keys -> conflict-free
    #pragma unroll
    for (int e = 0; e < 8; ++e)
      sm.s.Vt[buf][(wid * 8 + e) * 72 + lane] = vreg[e];
  };

  stageK(0, 0);
  loadV(0);
  writeV(0);
  __syncthreads();

  int cur = 0;
  for (int kt = 0; kt < NT; ++kt) {
    const bool pf = (kt + 1 < NT);
    if (pf) { stageK(cur ^ 1, (kt + 1) * 64); loadV((kt + 1) * 64); }

    // ---- K frags (A-operand) + QK^T ----
    short8 kf[2][4];
    #pragma unroll
    for (int tt = 0; tt < 2; ++tt)
      #pragma unroll
      for (int s = 0; s < 4; ++s) {
        int row = tt * 32 + lo;
        int byte = ((row << 7) + (s << 5) + (hi << 4)) ^ ((row & 7) << 4);
        kf[tt][s] = *reinterpret_cast<const short8*>((const char*)(&sm.s.Kl[cur][0]) + byte);
      }
    f32x16 st0, st1;
    #pragma unroll
    for (int r = 0; r < 16; ++r) { st0[r] = 0.f; st1[r] = 0.f; }
    #pragma unroll
    for (int s = 0; s < 4; ++s) {
      st0 = mfma32(kf[0][s], qf[s], st0);
      st1 = mfma32(kf[1][s], qf[s], st1);
    }

    // ---- online softmax (log2 domain), lane-local q ----
    float mx = st0[0];
    #pragma unroll
    for (int r = 1; r < 16; ++r) mx = fmaxf(mx, st0[r]);
    #pragma unroll
    for (int r = 0; r < 16; ++r) mx = fmaxf(mx, st1[r]);
    mx = fmaxf(mx, __shfl_xor(mx, 32));
    if (!__all(mx - m <= 8.0f)) {      // T13 defer-max
      float mn = fmaxf(m, mx);
      float sc = fexp2(m - mn);
      m = mn; l *= sc;
      o0 = o0 * sc; o1 = o1 * sc;
    }
    float ssum = 0.f;
    #pragma unroll
    for (int r = 0; r < 16; ++r) { float e = fexp2(st0[r] - m); st0[r] = e; ssum += e; }
    #pragma unroll
    for (int r = 0; r < 16; ++r) { float e = fexp2(st1[r] - m); st1[r] = e; ssum += e; }
    ssum += __shfl_xor(ssum, 32);
    l += ssum;

    // ---- P -> bf16 B-frags: cvt_pk + cross-half shfl_xor redistribution ----
    // target B-frag word w of pb[ks]: keys ks*16 + hi*8 + 2w, +2w+1 @ q=lo
    short8 pb[4];
    #pragma unroll
    for (int tt = 0; tt < 2; ++tt) {
      const f32x16& sv = tt ? st1 : st0;
      #pragma unroll
      for (int half = 0; half < 2; ++half) {
        unsigned x1 = cvtpk(sv[half * 8 + 0], sv[half * 8 + 1]);   // keys +0,+1 (+4hi)
        unsigned x2 = cvtpk(sv[half * 8 + 2], sv[half * 8 + 3]);   // keys +2,+3
        unsigned x3 = cvtpk(sv[half * 8 + 4], sv[half * 8 + 5]);   // keys +8,+9
        unsigned x4 = cvtpk(sv[half * 8 + 6], sv[half * 8 + 7]);   // keys +10,+11
        unsigned y1 = __shfl_xor(x1, 32);
        unsigned y2 = __shfl_xor(x2, 32);
        unsigned y3 = __shfl_xor(x3, 32);
        unsigned y4 = __shfl_xor(x4, 32);
        union { unsigned u[4]; short8 s8; } p;
        p.u[0] = hi ? y3 : x1;   // w0: keys +8hi+0,1
        p.u[1] = hi ? y4 : x2;   // w1: keys +8hi+2,3
        p.u[2] = hi ? x3 : y1;   // w2: keys +8hi+4,5
        p.u[3] = hi ? x4 : y2;   // w3: keys +8hi+6,7
        pb[tt * 2 + half] = p.s8;
      }
    }

    // ---- V^T frags (A-operand) + PV ----
    #pragma unroll
    for (int ks = 0; ks < 4; ++ks) {
      {
        int byte = (lo * 144) + (ks << 5) + (hi << 4);
        short8 va = *reinterpret_cast<const short8*>((const char*)(&sm.s.Vt[cur][0]) + byte);
        o0 = mfma32(va, pb[ks], o0);
      }
      {
        int byte = ((32 + lo) * 144) + (ks << 5) + (hi << 4);
        short8 va = *reinterpret_cast<const short8*>((const char*)(&sm.s.Vt[cur][0]) + byte);
        o1 = mfma32(va, pb[ks], o1);
      }
    }

    if (pf) writeV(cur ^ 1);
    __syncthreads();
    cur ^= 1;
  }

  // ---- epilogue: normalize, transpose via LDS, coalesced store ----
  float inv = 1.0f / l;
  #pragma unroll
  for (int dt = 0; dt < 2; ++dt) {
    const f32x16& ov = dt ? o1 : o0;
    #pragma unroll
    for (int r = 0; r < 16; r += 2) {
      unsigned d2 = cvtpk(ov[r] * inv, ov[r + 1] * inv);
      int dpos = dt * 32 + (r & 3) + 8 * (r >> 2) + 4 * hi;   // even
      *reinterpret_cast<unsigned*>((char*)(&sm.Ol[wid][0]) + (lo * 72 + dpos) * 2) = d2;
    }
  }
  __syncthreads();
  #pragma unroll
  for (int i = 0; i < 4; ++i) {
    int c = hi * 4 + i;
    short8 v = *reinterpret_cast<const short8*>((const char*)(&sm.Ol[wid][0]) + lo * 144 + c * 16);
    *reinterpret_cast<short8*>(Op + qrow * 2048 + h * 64 + c * 8) = v;
  }
}

// ---------------- launch (R5's validated dataflow) ----------------
// Workspace lifetime plan (total 62914560 B):
//   [0      ..  8M)  q_wb
//   [8M     .. 10M)  k_wb
//   [10M    .. 12M)  v_wb
//   [12M    .. 20M)  o_wb
//   R1 [20M .. 36M)  kx (key bf16)  -> qx (query bf16, after KV-proj) -> Ap (attn out)
//   R2 [36M .. 52M)  vx (value bf16) -> Qp (Q-proj out, after KV-proj)
//   [52M    .. 56M)  Kp
//   [56M    .. 60M)  Vp
extern "C" void kernel_launch(void* const* d_in, const int* in_sizes, int n_in,
                              void* d_out, int out_size, void* d_ws, size_t ws_size,
                              hipStream_t stream)
{
  const float* query = (const float*)d_in[0];
  const float* key   = (const float*)d_in[1];
  const float* value = (const float*)d_in[2];
  const float* q_w   = (const float*)d_in[3];
  const float* q_b   = (const float*)d_in[4];
  const float* k_w   = (const float*)d_in[5];
  const float* k_b   = (const float*)d_in[6];
  const float* v_w   = (const float*)d_in[7];
  const float* v_b   = (const float*)d_in[8];
  const float* o_w   = (const float*)d_in[9];
  const float* o_b   = (const float*)d_in[10];
  float* out = (float*)d_out;

  char* ws = (char*)d_ws;
  short* q_wb = (short*)(ws);
  short* k_wb = (short*)(ws + 8388608);
  short* v_wb = (short*)(ws + 10485760);
  short* o_wb = (short*)(ws + 12582912);
  short* R1   = (short*)(ws + 20971520);   // kx -> qx -> Ap
  short* R2   = (short*)(ws + 37748736);   // vx -> Qp
  short* Kp   = (short*)(ws + 54525952);
  short* Vp   = (short*)(ws + 58720256);

  const float ALPHA_Q = 0.125f * 1.4426950408889634f;  // SCALE * log2(e)

  // weight conversions (batched) + key/value activation conversions
  k_cvt2<<<dim3(4096, 1, 2), 256, 0, stream>>>(q_w, q_wb, o_w, o_wb, 1048576);
  k_cvt2<<<dim3(1024, 1, 2), 256, 0, stream>>>(k_w, k_wb, v_w, v_wb, 262144);
  k_cvt2<<<dim3(8192, 1, 2), 256, 0, stream>>>(key, R1, value, R2, 2097152);

  // fused K-proj / V-proj (reads kx=R1, vx=R2; writes Kp, Vp)
  k_gemm<false, true><<<dim3(4, 32, 2), 256, 0, stream>>>(
      R1, k_wb, k_b, Kp, R2, v_wb, v_b, Vp, 4096, 512, 2048, 1.0f);

  // query -> bf16 into R1 (kx dead after KV-proj)
  k_cvt<<<8192, 256, 0, stream>>>(query, R1, 2097152);

  // Q-proj (reads qx=R1; writes Qp=R2; vx dead)
  k_gemm<false, false><<<dim3(16, 32), 256, 0, stream>>>(
      R1, q_wb, q_b, R2, nullptr, nullptr, nullptr, nullptr, 4096, 2048, 2048, ALPHA_Q);

  // attention (reads Qp=R2, Kp, Vp; writes Ap=R1; qx dead)
  k_attn<<<dim3(512), dim3(512), 0, stream>>>(R2, Kp, Vp, R1);

  // O-proj (reads Ap=R1; writes out)
  k_gemm<true, false><<<dim3(16, 32), 256, 0, stream>>>(
      R1, o_wb, o_b, out, nullptr, nullptr, nullptr, nullptr, 4096, 2048, 2048, 1.0f);
}